// Round 1
// baseline (516.697 us; speedup 1.0000x reference)
//
#include <hip/hip_runtime.h>
#include <hip/hip_bf16.h>
#include <stdint.h>

#define DIMM 2048
#define HIDD 1024
#define NEXP 8
#define TOPK 2
#define NTOK 2048
#define CAP_E 1024
#define CAP_T (NEXP * CAP_E)

typedef __bf16 bf16_t;
typedef __bf16 bf16x4 __attribute__((ext_vector_type(4)));
typedef __bf16 bf16x8 __attribute__((ext_vector_type(8)));
typedef float f32x4 __attribute__((ext_vector_type(4)));

__device__ __forceinline__ void gl2lds16(const bf16_t* g, bf16_t* l) {
    __builtin_amdgcn_global_load_lds(
        (const __attribute__((address_space(1))) void*)g,
        (__attribute__((address_space(3))) void*)l, 16, 0, 0);
}

// ---------------- fp32 -> bf16 converts ----------------
__global__ __launch_bounds__(256) void conv_f2b(const float* __restrict__ s,
                                                bf16_t* __restrict__ d, int n4) {
    int i = blockIdx.x * 256 + threadIdx.x;
    if (i >= n4) return;
    float4 v = ((const float4*)s)[i];
    bf16x4 o = {(bf16_t)v.x, (bf16_t)v.y, (bf16_t)v.z, (bf16_t)v.w};
    ((bf16x4*)d)[i] = o;
}

// w13b[e] rows 0..1023 = w1[e], rows 1024..2047 = w3[e]
__global__ __launch_bounds__(256) void conv_w13(const float* __restrict__ w1,
                                                const float* __restrict__ w3,
                                                bf16_t* __restrict__ d, int n4) {
    int i = blockIdx.x * 256 + threadIdx.x;
    if (i >= n4) return;
    long flat = (long)i * 4;
    int e = (int)(flat >> 22);            // 2048*2048 = 2^22
    int rem = (int)(flat & ((1 << 22) - 1));
    int r = rem >> 11;
    int dd = rem & 2047;
    const float* src = (r < HIDD)
        ? (w1 + ((long)e << 21) + ((long)r << 11) + dd)
        : (w3 + ((long)e << 21) + ((long)(r - HIDD) << 11) + dd);
    float4 v = *(const float4*)src;
    bf16x4 o = {(bf16_t)v.x, (bf16_t)v.y, (bf16_t)v.z, (bf16_t)v.w};
    ((bf16x4*)d)[i] = o;
}

// ---------------- router: sigmoid(x @ gw^T), top-2 with bias ----------------
__global__ __launch_bounds__(256) void router_k(const float* __restrict__ x,
                                                const float* __restrict__ gw,
                                                const float* __restrict__ bias,
                                                int* __restrict__ sel,
                                                float* __restrict__ topsc) {
    int t = blockIdx.x;
    int tid = threadIdx.x;
    const float* xr = x + (long)t * DIMM;
    double acc[NEXP];
#pragma unroll
    for (int e = 0; e < NEXP; ++e) acc[e] = 0.0;
    for (int d = tid; d < DIMM; d += 256) {
        double xv = (double)xr[d];
#pragma unroll
        for (int e = 0; e < NEXP; ++e) acc[e] += xv * (double)gw[e * DIMM + d];
    }
#pragma unroll
    for (int off = 32; off >= 1; off >>= 1)
#pragma unroll
        for (int e = 0; e < NEXP; ++e) acc[e] += __shfl_down(acc[e], off, 64);
    __shared__ double red[4][NEXP];
    int lane = tid & 63, w = tid >> 6;
    if (lane == 0)
#pragma unroll
        for (int e = 0; e < NEXP; ++e) red[w][e] = acc[e];
    __syncthreads();
    if (tid == 0) {
        double sc[NEXP], v[NEXP];
#pragma unroll
        for (int e = 0; e < NEXP; ++e) {
            double s = red[0][e] + red[1][e] + red[2][e] + red[3][e];
            sc[e] = 1.0 / (1.0 + exp(-s));
            v[e] = sc[e] + (double)bias[e];
        }
        int b0 = 0;
        for (int e = 1; e < NEXP; ++e) if (v[e] > v[b0]) b0 = e;
        int b1 = -1;
        for (int e = 0; e < NEXP; ++e)
            if (e != b0 && (b1 < 0 || v[e] > v[b1])) b1 = e;
        sel[t * 2] = b0; sel[t * 2 + 1] = b1;
        topsc[t * 2] = (float)sc[b0]; topsc[t * 2 + 1] = (float)sc[b1];
    }
}

// ---------------- stable counting sort into per-expert segments ----------------
__global__ __launch_bounds__(256) void sort_k(const int* __restrict__ sel,
                                              const float* __restrict__ topsc,
                                              int* __restrict__ tok_s,
                                              float* __restrict__ sc_s,
                                              int* __restrict__ counts) {
    __shared__ int se[NTOK * TOPK];
    int tid = threadIdx.x;
    for (int i = tid; i < NTOK * TOPK; i += 256) se[i] = sel[i];
    __syncthreads();
    int wv = tid >> 6, lane = tid & 63;
    unsigned long long lower = (1ull << lane) - 1ull;
    for (int ei = 0; ei < 2; ++ei) {
        int e = wv * 2 + ei;
        int base = e * CAP_E;
        int off = 0;
        for (int c = 0; c < (NTOK * TOPK) / 64; ++c) {
            int slot = c * 64 + lane;
            bool m = (se[slot] == e);
            unsigned long long bal = __ballot(m);
            if (m) {
                int rank = off + __popcll(bal & lower);
                if (rank < CAP_E) {
                    tok_s[base + rank] = slot >> 1;  // TOPK = 2
                    sc_s[base + rank] = topsc[slot];
                }
            }
            off += __popcll(bal);
        }
        int cnt = min(off, CAP_E);
        if (lane == 0) counts[e] = cnt;
        int padded = min((cnt + 127) & ~127, CAP_E);
        for (int r = cnt + lane; r < padded; r += 64) tok_s[base + r] = -1;
    }
}

// ---------------- gather + scale -> rin bf16 (pad rows zeroed) ----------------
__global__ __launch_bounds__(256) void build_rin(const float* __restrict__ x,
                                                 const int* __restrict__ tok_s,
                                                 const float* __restrict__ sc_s,
                                                 const int* __restrict__ counts,
                                                 bf16_t* __restrict__ rin) {
    int row = blockIdx.x;
    int e = row >> 10, r = row & (CAP_E - 1);
    int cnt = min(counts[e], CAP_E);
    int padded = min((cnt + 127) & ~127, CAP_E);
    if (r >= padded) return;
    int d0 = threadIdx.x * 8;
    bf16x8 o;
    if (r < cnt) {
        int tok = tok_s[row];
        float sc = sc_s[row];
        const float* src = x + (long)tok * DIMM + d0;
        float4 a = *(const float4*)src;
        float4 b = *(const float4*)(src + 4);
        o[0] = (bf16_t)(a.x * sc); o[1] = (bf16_t)(a.y * sc);
        o[2] = (bf16_t)(a.z * sc); o[3] = (bf16_t)(a.w * sc);
        o[4] = (bf16_t)(b.x * sc); o[5] = (bf16_t)(b.y * sc);
        o[6] = (bf16_t)(b.z * sc); o[7] = (bf16_t)(b.w * sc);
    } else {
#pragma unroll
        for (int i = 0; i < 8; ++i) o[i] = (bf16_t)0.0f;
    }
    *(bf16x8*)(rin + (long)row * DIMM + d0) = o;
}

// ---------------- C = A @ B^T, 128x128 tile, 16x16x32 bf16 MFMA ----------------
// EPI: 0 = bf16 store, 1 = f32 store, 2 = atomic scatter-add to outp[tok]
template <int EPI>
__global__ __launch_bounds__(256, 2) void gemm_bt(
    const bf16_t* __restrict__ A0, const bf16_t* __restrict__ B0,
    void* __restrict__ C0, const int* __restrict__ counts, int Mfixed,
    int N, int K, long sA, long sB, long sC,
    const int* __restrict__ tok_s, float* __restrict__ outp) {
    int e = blockIdx.z;
    int M = Mfixed;
    if (counts) {
        int c = min(counts[e], Mfixed);
        M = min((c + 127) & ~127, Mfixed);
    }
    int m0 = blockIdx.y * 128;
    if (m0 >= M) return;
    int n0 = blockIdx.x * 128;
    const bf16_t* A = A0 + (long)e * sA;
    const bf16_t* B = B0 + (long)e * sB;

    __shared__ bf16_t lA[128 * 64];
    __shared__ bf16_t lB[128 * 64];

    int tid = threadIdx.x;
    int lane = tid & 63, wv = tid >> 6;
    int quad = lane >> 4, l16 = lane & 15;
    int wm = (wv & 1) * 64, wn = (wv >> 1) * 64;

    f32x4 acc[4][4];
#pragma unroll
    for (int i = 0; i < 4; ++i)
#pragma unroll
        for (int j = 0; j < 4; ++j) acc[i][j] = (f32x4){0.f, 0.f, 0.f, 0.f};

    int kTiles = K >> 6;
    for (int kt = 0; kt < kTiles; ++kt) {
        int kb = kt << 6;
        // stage A,B tiles: lds chunk q holds global chunk (q&7)^(row&7) of row q>>3
#pragma unroll
        for (int i = 0; i < 4; ++i) {
            int q = i * 256 + tid;
            int row = q >> 3, cc = q & 7;
            int scc = cc ^ (row & 7);
            gl2lds16(A + (long)(m0 + row) * K + kb + scc * 8, &lA[q * 8]);
            gl2lds16(B + (long)(n0 + row) * K + kb + scc * 8, &lB[q * 8]);
        }
        __syncthreads();
#pragma unroll
        for (int ki = 0; ki < 2; ++ki) {
            bf16x8 af[4], bfr[4];
            int kc = ki * 4 + quad;
#pragma unroll
            for (int mi = 0; mi < 4; ++mi) {
                int row = wm + mi * 16 + l16;
                int chunk = row * 8 + (kc ^ (row & 7));
                af[mi] = *(const bf16x8*)&lA[chunk * 8];
            }
#pragma unroll
            for (int ni = 0; ni < 4; ++ni) {
                int row = wn + ni * 16 + l16;
                int chunk = row * 8 + (kc ^ (row & 7));
                bfr[ni] = *(const bf16x8*)&lB[chunk * 8];
            }
#pragma unroll
            for (int mi = 0; mi < 4; ++mi)
#pragma unroll
                for (int ni = 0; ni < 4; ++ni)
                    acc[mi][ni] = __builtin_amdgcn_mfma_f32_16x16x32_bf16(
                        af[mi], bfr[ni], acc[mi][ni], 0, 0, 0);
        }
        __syncthreads();
    }

    if (EPI == 0) {
        bf16_t* Cp = (bf16_t*)C0 + (long)e * sC;
#pragma unroll
        for (int mi = 0; mi < 4; ++mi)
#pragma unroll
            for (int r = 0; r < 4; ++r) {
                int row = m0 + wm + mi * 16 + quad * 4 + r;
#pragma unroll
                for (int ni = 0; ni < 4; ++ni) {
                    int col = n0 + wn + ni * 16 + l16;
                    Cp[(long)row * N + col] = (bf16_t)acc[mi][ni][r];
                }
            }
    } else if (EPI == 1) {
        float* Cp = (float*)C0;
#pragma unroll
        for (int mi = 0; mi < 4; ++mi)
#pragma unroll
            for (int r = 0; r < 4; ++r) {
                int row = m0 + wm + mi * 16 + quad * 4 + r;
#pragma unroll
                for (int ni = 0; ni < 4; ++ni) {
                    int col = n0 + wn + ni * 16 + l16;
                    Cp[(long)row * N + col] = acc[mi][ni][r];
                }
            }
    } else {
#pragma unroll
        for (int mi = 0; mi < 4; ++mi)
#pragma unroll
            for (int r = 0; r < 4; ++r) {
                int rloc = m0 + wm + mi * 16 + quad * 4 + r;
                int tok = tok_s[e * CAP_E + rloc];
                if (tok >= 0) {
                    float* op = outp + (long)tok * DIMM + n0 + wn + l16;
#pragma unroll
                    for (int ni = 0; ni < 4; ++ni)
                        atomicAdd(op + ni * 16, acc[mi][ni][r]);
                }
            }
    }
}

// ---------------- h = silu(ht[:, :1024]) * ht[:, 1024:] ----------------
__global__ __launch_bounds__(256) void silu_comb(const bf16_t* __restrict__ ht,
                                                 bf16_t* __restrict__ h,
                                                 const int* __restrict__ counts) {
    int row = blockIdx.x;
    if (counts) {
        int e = row >> 10, r = row & (CAP_E - 1);
        int cnt = min(counts[e], CAP_E);
        int padded = min((cnt + 127) & ~127, CAP_E);
        if (r >= padded) return;
    }
    int j = threadIdx.x * 4;
    bf16x4 a4 = *(const bf16x4*)&ht[(long)row * 2048 + j];
    bf16x4 b4 = *(const bf16x4*)&ht[(long)row * 2048 + 1024 + j];
    bf16x4 o;
#pragma unroll
    for (int i = 0; i < 4; ++i) {
        float a = (float)a4[i], b = (float)b4[i];
        float s = a / (1.f + expf(-a));
        o[i] = (bf16_t)(s * b);
    }
    *(bf16x4*)&h[(long)row * 1024 + j] = o;
}

extern "C" void kernel_launch(void* const* d_in, const int* in_sizes, int n_in,
                              void* d_out, int out_size, void* d_ws, size_t ws_size,
                              hipStream_t stream) {
    const float* x    = (const float*)d_in[0];
    const float* bias = (const float*)d_in[1];
    const float* gw   = (const float*)d_in[2];
    const float* w1   = (const float*)d_in[3];
    const float* w2   = (const float*)d_in[4];
    const float* w3   = (const float*)d_in[5];
    const float* sw1  = (const float*)d_in[6];
    const float* sw2  = (const float*)d_in[7];
    const float* sw3  = (const float*)d_in[8];
    float* out = (float*)d_out;

    char* p = (char*)d_ws;
    auto alloc = [&](size_t bytes) {
        char* r = p;
        p += (bytes + 255) & ~(size_t)255;
        return r;
    };
    bf16_t* xb    = (bf16_t*)alloc((size_t)NTOK * DIMM * 2);
    bf16_t* w13b  = (bf16_t*)alloc((size_t)NEXP * 2048 * 2048 * 2);
    bf16_t* w2b   = (bf16_t*)alloc((size_t)NEXP * 2048 * 1024 * 2);
    bf16_t* sw13b = (bf16_t*)alloc((size_t)2048 * 2048 * 2);
    bf16_t* sw2b  = (bf16_t*)alloc((size_t)2048 * 1024 * 2);
    bf16_t* rin   = (bf16_t*)alloc((size_t)CAP_T * DIMM * 2);
    bf16_t* ht    = (bf16_t*)alloc((size_t)CAP_T * 2048 * 2);
    bf16_t* hB    = (bf16_t*)alloc((size_t)CAP_T * 1024 * 2);
    bf16_t* sht   = (bf16_t*)alloc((size_t)NTOK * 2048 * 2);
    bf16_t* shB   = (bf16_t*)alloc((size_t)NTOK * 1024 * 2);
    int*   sel    = (int*)alloc(NTOK * TOPK * 4);
    float* topsc  = (float*)alloc(NTOK * TOPK * 4);
    int*   tok_s  = (int*)alloc(CAP_T * 4);
    float* sc_s   = (float*)alloc(CAP_T * 4);
    int*   counts = (int*)alloc(256);

    int n4;
    n4 = NTOK * DIMM / 4;
    conv_f2b<<<n4 / 256, 256, 0, stream>>>(x, xb, n4);
    n4 = NEXP * 2048 * 2048 / 4;
    conv_w13<<<n4 / 256, 256, 0, stream>>>(w1, w3, w13b, n4);
    n4 = NEXP * 2048 * 1024 / 4;
    conv_f2b<<<n4 / 256, 256, 0, stream>>>(w2, w2b, n4);
    n4 = HIDD * 2048 / 4;
    conv_f2b<<<n4 / 256, 256, 0, stream>>>(sw1, sw13b, n4);
    conv_f2b<<<n4 / 256, 256, 0, stream>>>(sw3, sw13b + (size_t)HIDD * 2048, n4);
    n4 = 2048 * 1024 / 4;
    conv_f2b<<<n4 / 256, 256, 0, stream>>>(sw2, sw2b, n4);

    router_k<<<NTOK, 256, 0, stream>>>(x, gw, bias, sel, topsc);
    sort_k<<<1, 256, 0, stream>>>(sel, topsc, tok_s, sc_s, counts);
    build_rin<<<CAP_T, 256, 0, stream>>>(x, tok_s, sc_s, counts, rin);

    // GEMM1 routed: ht[e] = rin[e] @ w13[e]^T   (M<=1024, N=2048, K=2048)
    gemm_bt<0><<<dim3(16, CAP_E / 128, NEXP), 256, 0, stream>>>(
        rin, w13b, ht, counts, CAP_E, 2048, 2048,
        (long)CAP_E * 2048, (long)2048 * 2048, (long)CAP_E * 2048, nullptr, nullptr);
    // GEMM1 shared: sht = xb @ sw13^T   (2048 x 2048 x 2048)
    gemm_bt<0><<<dim3(16, 16, 1), 256, 0, stream>>>(
        xb, sw13b, sht, nullptr, 2048, 2048, 2048, 0, 0, 0, nullptr, nullptr);

    silu_comb<<<CAP_T, 256, 0, stream>>>(ht, hB, counts);
    silu_comb<<<NTOK, 256, 0, stream>>>(sht, shB, nullptr);

    // GEMM2 shared: out = shB @ sw2^T (plain store, full overwrite)
    gemm_bt<1><<<dim3(16, 16, 1), 256, 0, stream>>>(
        shB, sw2b, out, nullptr, 2048, 2048, 1024, 0, 0, 0, nullptr, nullptr);
    // GEMM2 routed: out[tok] += hB[e] @ w2[e]^T (atomic scatter)
    gemm_bt<2><<<dim3(16, CAP_E / 128, NEXP), 256, 0, stream>>>(
        hB, w2b, nullptr, counts, CAP_E, 2048, 1024,
        (long)CAP_E * 1024, (long)2048 * 1024, 0, tok_s, out);
}

// Round 2
// 479.407 us; speedup vs baseline: 1.0778x; 1.0778x over previous
//
#include <hip/hip_runtime.h>
#include <hip/hip_bf16.h>
#include <stdint.h>

#define DIMM 2048
#define HIDD 1024
#define NEXP 8
#define TOPK 2
#define NTOK 2048
#define CAP_E 1024
#define SH_BASE (NEXP * CAP_E)        // 8192
#define NROW (SH_BASE + NTOK)         // 10240

typedef __bf16 bf16_t;
typedef __bf16 bf16x4 __attribute__((ext_vector_type(4)));
typedef __bf16 bf16x8 __attribute__((ext_vector_type(8)));
typedef float f32x4 __attribute__((ext_vector_type(4)));

__device__ __forceinline__ void gl2lds16(const bf16_t* g, bf16_t* l) {
    __builtin_amdgcn_global_load_lds(
        (const __attribute__((address_space(1))) void*)g,
        (__attribute__((address_space(3))) void*)l, 16, 0, 0);
}

// ---------------- zero d_out ----------------
__global__ __launch_bounds__(256) void zero_f(float* __restrict__ p, int n4) {
    int i = blockIdx.x * 256 + threadIdx.x;
    if (i < n4) ((float4*)p)[i] = (float4){0.f, 0.f, 0.f, 0.f};
}

// ---------------- router: sigmoid(x @ gw^T), top-2 with bias ----------------
__global__ __launch_bounds__(256) void router_k(const float* __restrict__ x,
                                                const float* __restrict__ gw,
                                                const float* __restrict__ bias,
                                                int* __restrict__ sel,
                                                float* __restrict__ topsc) {
    int t = blockIdx.x;
    int tid = threadIdx.x;
    const float* xr = x + (long)t * DIMM;
    double acc[NEXP];
#pragma unroll
    for (int e = 0; e < NEXP; ++e) acc[e] = 0.0;
    for (int d = tid; d < DIMM; d += 256) {
        double xv = (double)xr[d];
#pragma unroll
        for (int e = 0; e < NEXP; ++e) acc[e] += xv * (double)gw[e * DIMM + d];
    }
#pragma unroll
    for (int off = 32; off >= 1; off >>= 1)
#pragma unroll
        for (int e = 0; e < NEXP; ++e) acc[e] += __shfl_down(acc[e], off, 64);
    __shared__ double red[4][NEXP];
    int lane = tid & 63, w = tid >> 6;
    if (lane == 0)
#pragma unroll
        for (int e = 0; e < NEXP; ++e) red[w][e] = acc[e];
    __syncthreads();
    if (tid == 0) {
        double sc[NEXP], v[NEXP];
#pragma unroll
        for (int e = 0; e < NEXP; ++e) {
            double s = red[0][e] + red[1][e] + red[2][e] + red[3][e];
            sc[e] = 1.0 / (1.0 + exp(-s));
            v[e] = sc[e] + (double)bias[e];
        }
        int b0 = 0;
        for (int e = 1; e < NEXP; ++e) if (v[e] > v[b0]) b0 = e;
        int b1 = -1;
        for (int e = 0; e < NEXP; ++e)
            if (e != b0 && (b1 < 0 || v[e] > v[b1])) b1 = e;
        sel[t * 2] = b0; sel[t * 2 + 1] = b1;
        topsc[t * 2] = (float)sc[b0]; topsc[t * 2 + 1] = (float)sc[b1];
    }
}

// ---------------- stable counting sort into per-expert segments ----------------
__global__ __launch_bounds__(256) void sort_k(const int* __restrict__ sel,
                                              const float* __restrict__ topsc,
                                              int* __restrict__ tok_s,
                                              float* __restrict__ sc_s,
                                              int* __restrict__ counts) {
    __shared__ int se[NTOK * TOPK];
    int tid = threadIdx.x;
    for (int i = tid; i < NTOK * TOPK; i += 256) se[i] = sel[i];
    __syncthreads();
    int wv = tid >> 6, lane = tid & 63;
    unsigned long long lower = (1ull << lane) - 1ull;
    for (int ei = 0; ei < 2; ++ei) {
        int e = wv * 2 + ei;
        int base = e * CAP_E;
        int off = 0;
        for (int c = 0; c < (NTOK * TOPK) / 64; ++c) {
            int slot = c * 64 + lane;
            bool m = (se[slot] == e);
            unsigned long long bal = __ballot(m);
            if (m) {
                int rank = off + __popcll(bal & lower);
                if (rank < CAP_E) {
                    tok_s[base + rank] = slot >> 1;  // TOPK = 2
                    sc_s[base + rank] = topsc[slot];
                }
            }
            off += __popcll(bal);
        }
        int cnt = min(off, CAP_E);
        if (lane == 0) counts[e] = cnt;
        int padded = min((cnt + 127) & ~127, CAP_E);
        for (int r = cnt + lane; r < padded; r += 64) tok_s[base + r] = -1;
    }
}

// ---------- gather + scale -> rin bf16 (routed segs + shared block) ----------
__global__ __launch_bounds__(256) void build_rin(const float* __restrict__ x,
                                                 const int* __restrict__ tok_s,
                                                 const float* __restrict__ sc_s,
                                                 const int* __restrict__ counts,
                                                 bf16_t* __restrict__ rin) {
    int row = blockIdx.x;
    int tok; float sc = 1.0f;
    if (row >= SH_BASE) {
        tok = row - SH_BASE;
    } else {
        int e = row >> 10, r = row & (CAP_E - 1);
        int cnt = min(counts[e], CAP_E);
        int padded = min((cnt + 127) & ~127, CAP_E);
        if (r >= padded) return;
        if (r < cnt) { tok = tok_s[row]; sc = sc_s[row]; }
        else tok = -1;
    }
    int d0 = threadIdx.x * 8;
    bf16x8 o;
    if (tok >= 0) {
        const float* src = x + (long)tok * DIMM + d0;
        float4 a = *(const float4*)src;
        float4 b = *(const float4*)(src + 4);
        o[0] = (bf16_t)(a.x * sc); o[1] = (bf16_t)(a.y * sc);
        o[2] = (bf16_t)(a.z * sc); o[3] = (bf16_t)(a.w * sc);
        o[4] = (bf16_t)(b.x * sc); o[5] = (bf16_t)(b.y * sc);
        o[6] = (bf16_t)(b.z * sc); o[7] = (bf16_t)(b.w * sc);
    } else {
#pragma unroll
        for (int i = 0; i < 8; ++i) o[i] = (bf16_t)0.0f;
    }
    *(bf16x8*)(rin + (long)row * DIMM + d0) = o;
}

// ------------- grouped GEMM, fused fp32->bf16 B-staging -------------
// PHASE 1: K=2048, B row n -> w1[g] rows [0,1024) / w3[g] rows [1024,2048),
//          shared group 8 uses sw1/sw3. bf16 store to Cout.
// PHASE 2: K=1024, B = w2[g] (2048x1024), shared uses sw2.
//          fp32 atomic scatter-add to outp via tok_s.
template <int PHASE>
__global__ __launch_bounds__(256, 2) void gemm_moe(
    const bf16_t* __restrict__ A0,
    const float* __restrict__ W1, const float* __restrict__ W3,
    const float* __restrict__ SW1, const float* __restrict__ SW3,
    bf16_t* __restrict__ Cout, float* __restrict__ outp,
    const int* __restrict__ counts, const int* __restrict__ tok_s) {
    constexpr int K = (PHASE == 1) ? 2048 : 1024;
    int g = blockIdx.z;
    int base = (g < 8) ? g * CAP_E : SH_BASE;
    int M = NTOK;
    if (g < 8) {
        int c = min(counts[g], CAP_E);
        M = min((c + 127) & ~127, CAP_E);
    }
    int m0 = blockIdx.y * 128;
    if (m0 >= M) return;
    int n0 = blockIdx.x * 128;
    const bf16_t* A = A0 + (long)base * K;

    __shared__ bf16_t lA[128 * 64];
    __shared__ bf16_t lB[128 * 64];

    int tid = threadIdx.x;
    int lane = tid & 63, wv = tid >> 6;
    int quad = lane >> 4, l16 = lane & 15;
    int wm = (wv & 1) * 64, wn = (wv >> 1) * 64;
    int cc = tid & 7;
    int rbase = tid >> 3;

    // per-thread B row pointers + swizzled LDS slots for the 4 staging rows
    const float* brow[4];
    int slot[4];
#pragma unroll
    for (int i = 0; i < 4; ++i) {
        int row = i * 32 + rbase;
        int n = n0 + row;
        const float* p;
        if (PHASE == 1) {
            if (g < 8) p = (n < HIDD) ? W1 + ((long)g << 21) + (long)n * DIMM
                                      : W3 + ((long)g << 21) + (long)(n - HIDD) * DIMM;
            else       p = (n < HIDD) ? SW1 + (long)n * DIMM
                                      : SW3 + (long)(n - HIDD) * DIMM;
        } else {
            p = (g < 8) ? W1 + ((long)g << 21) + (long)n * HIDD
                        : SW1 + (long)n * HIDD;
        }
        brow[i] = p + cc * 8;
        slot[i] = row * 8 + (cc ^ (row & 7));
    }

    f32x4 acc[4][4];
#pragma unroll
    for (int i = 0; i < 4; ++i)
#pragma unroll
        for (int j = 0; j < 4; ++j) acc[i][j] = (f32x4){0.f, 0.f, 0.f, 0.f};

    for (int kt = 0; kt < K / 64; ++kt) {
        int kb = kt * 64;
        // A: bf16 async global->LDS, swizzled source chunk
#pragma unroll
        for (int i = 0; i < 4; ++i) {
            int row = i * 32 + rbase;
            int scc = cc ^ (row & 7);
            gl2lds16(A + (long)(m0 + row) * K + kb + scc * 8, &lA[(i * 256 + tid) * 8]);
        }
        // B: fp32 -> regs -> bf16 -> swizzled ds_write
        float4 u[4], v[4];
#pragma unroll
        for (int i = 0; i < 4; ++i) {
            const float* p = brow[i] + kb;
            u[i] = *(const float4*)p;
            v[i] = *(const float4*)(p + 4);
        }
#pragma unroll
        for (int i = 0; i < 4; ++i) {
            bf16x8 o = {(bf16_t)u[i].x, (bf16_t)u[i].y, (bf16_t)u[i].z, (bf16_t)u[i].w,
                        (bf16_t)v[i].x, (bf16_t)v[i].y, (bf16_t)v[i].z, (bf16_t)v[i].w};
            *(bf16x8*)&lB[slot[i] * 8] = o;
        }
        __syncthreads();
#pragma unroll
        for (int ki = 0; ki < 2; ++ki) {
            bf16x8 af[4], bfr[4];
            int kc = ki * 4 + quad;
#pragma unroll
            for (int mi = 0; mi < 4; ++mi) {
                int row = wm + mi * 16 + l16;
                int chunk = row * 8 + (kc ^ (row & 7));
                af[mi] = *(const bf16x8*)&lA[chunk * 8];
            }
#pragma unroll
            for (int ni = 0; ni < 4; ++ni) {
                int row = wn + ni * 16 + l16;
                int chunk = row * 8 + (kc ^ (row & 7));
                bfr[ni] = *(const bf16x8*)&lB[chunk * 8];
            }
#pragma unroll
            for (int mi = 0; mi < 4; ++mi)
#pragma unroll
                for (int ni = 0; ni < 4; ++ni)
                    acc[mi][ni] = __builtin_amdgcn_mfma_f32_16x16x32_bf16(
                        af[mi], bfr[ni], acc[mi][ni], 0, 0, 0);
        }
        __syncthreads();
    }

    if (PHASE == 1) {
#pragma unroll
        for (int mi = 0; mi < 4; ++mi)
#pragma unroll
            for (int r = 0; r < 4; ++r) {
                int row = base + m0 + wm + mi * 16 + quad * 4 + r;
#pragma unroll
                for (int ni = 0; ni < 4; ++ni) {
                    int col = n0 + wn + ni * 16 + l16;
                    Cout[(long)row * DIMM + col] = (bf16_t)acc[mi][ni][r];
                }
            }
    } else {
#pragma unroll
        for (int mi = 0; mi < 4; ++mi)
#pragma unroll
            for (int r = 0; r < 4; ++r) {
                int rloc = m0 + wm + mi * 16 + quad * 4 + r;
                int tok = (g < 8) ? tok_s[g * CAP_E + rloc] : rloc;
                if (tok >= 0) {
                    float* op = outp + (long)tok * DIMM + n0 + wn + l16;
#pragma unroll
                    for (int ni = 0; ni < 4; ++ni)
                        atomicAdd(op + ni * 16, acc[mi][ni][r]);
                }
            }
    }
}

// ---------------- h = silu(ht[:, :1024]) * ht[:, 1024:] ----------------
__global__ __launch_bounds__(256) void silu_comb(const bf16_t* __restrict__ ht,
                                                 bf16_t* __restrict__ h,
                                                 const int* __restrict__ counts) {
    int row = blockIdx.x;
    if (row < SH_BASE) {
        int e = row >> 10, r = row & (CAP_E - 1);
        int cnt = min(counts[e], CAP_E);
        int padded = min((cnt + 127) & ~127, CAP_E);
        if (r >= padded) return;
    }
    int j = threadIdx.x * 4;
    bf16x4 a4 = *(const bf16x4*)&ht[(long)row * DIMM + j];
    bf16x4 b4 = *(const bf16x4*)&ht[(long)row * DIMM + HIDD + j];
    bf16x4 o;
#pragma unroll
    for (int i = 0; i < 4; ++i) {
        float a = (float)a4[i], b = (float)b4[i];
        float s = a / (1.f + expf(-a));
        o[i] = (bf16_t)(s * b);
    }
    *(bf16x4*)&h[(long)row * HIDD + j] = o;
}

extern "C" void kernel_launch(void* const* d_in, const int* in_sizes, int n_in,
                              void* d_out, int out_size, void* d_ws, size_t ws_size,
                              hipStream_t stream) {
    const float* x    = (const float*)d_in[0];
    const float* bias = (const float*)d_in[1];
    const float* gw   = (const float*)d_in[2];
    const float* w1   = (const float*)d_in[3];
    const float* w2   = (const float*)d_in[4];
    const float* w3   = (const float*)d_in[5];
    const float* sw1  = (const float*)d_in[6];
    const float* sw2  = (const float*)d_in[7];
    const float* sw3  = (const float*)d_in[8];
    float* out = (float*)d_out;

    char* p = (char*)d_ws;
    auto alloc = [&](size_t bytes) {
        char* r = p;
        p += (bytes + 255) & ~(size_t)255;
        return r;
    };
    bf16_t* rin   = (bf16_t*)alloc((size_t)NROW * DIMM * 2);   // 40 MB
    bf16_t* ht    = (bf16_t*)alloc((size_t)NROW * DIMM * 2);   // 40 MB
    bf16_t* hB    = (bf16_t*)alloc((size_t)NROW * HIDD * 2);   // 20 MB
    int*   sel    = (int*)alloc(NTOK * TOPK * 4);
    float* topsc  = (float*)alloc(NTOK * TOPK * 4);
    int*   tok_s  = (int*)alloc(SH_BASE * 4);
    float* sc_s   = (float*)alloc(SH_BASE * 4);
    int*   counts = (int*)alloc(256);

    zero_f<<<(NTOK * DIMM / 4) / 256, 256, 0, stream>>>(out, NTOK * DIMM / 4);
    router_k<<<NTOK, 256, 0, stream>>>(x, gw, bias, sel, topsc);
    sort_k<<<1, 256, 0, stream>>>(sel, topsc, tok_s, sc_s, counts);
    build_rin<<<NROW, 256, 0, stream>>>(x, tok_s, sc_s, counts, rin);

    // GEMM1: ht[g] = A[g] @ [w1;w3][g]^T   (9 groups, N=2048, K=2048)
    gemm_moe<1><<<dim3(16, 16, 9), 256, 0, stream>>>(
        rin, w1, w3, sw1, sw3, ht, nullptr, counts, nullptr);

    silu_comb<<<NROW, 256, 0, stream>>>(ht, hB, counts);

    // GEMM2: out[tok] += hB[g] @ w2[g]^T   (9 groups, N=2048, K=1024, atomic)
    gemm_moe<2><<<dim3(16, 16, 9), 256, 0, stream>>>(
        hB, w2, nullptr, sw2, nullptr, nullptr, out, counts, tok_s);
}

// Round 3
// 416.167 us; speedup vs baseline: 1.2416x; 1.1520x over previous
//
#include <hip/hip_runtime.h>
#include <hip/hip_bf16.h>
#include <stdint.h>

#define DIMM 2048
#define HIDD 1024
#define NEXP 8
#define TOPK 2
#define NTOK 2048
#define CAP_E 1024
#define SH_BASE (NEXP * CAP_E)        // 8192
#define NROW (SH_BASE + NTOK)         // 10240

typedef __bf16 bf16_t;
typedef __bf16 bf16x4 __attribute__((ext_vector_type(4)));
typedef __bf16 bf16x8 __attribute__((ext_vector_type(8)));
typedef float f32x4 __attribute__((ext_vector_type(4)));

__device__ __forceinline__ void gl2lds16(const bf16_t* g, bf16_t* l) {
    __builtin_amdgcn_global_load_lds(
        (const __attribute__((address_space(1))) void*)g,
        (__attribute__((address_space(3))) void*)l, 16, 0, 0);
}

// ---------------- router: sigmoid(x @ gw^T), top-2 with bias ----------------
__global__ __launch_bounds__(256) void router_k(const float* __restrict__ x,
                                                const float* __restrict__ gw,
                                                const float* __restrict__ bias,
                                                int* __restrict__ sel,
                                                float* __restrict__ topsc) {
    int t = blockIdx.x;
    int tid = threadIdx.x;
    const float* xr = x + (long)t * DIMM;
    double acc[NEXP];
#pragma unroll
    for (int e = 0; e < NEXP; ++e) acc[e] = 0.0;
    for (int d = tid; d < DIMM; d += 256) {
        double xv = (double)xr[d];
#pragma unroll
        for (int e = 0; e < NEXP; ++e) acc[e] += xv * (double)gw[e * DIMM + d];
    }
#pragma unroll
    for (int off = 32; off >= 1; off >>= 1)
#pragma unroll
        for (int e = 0; e < NEXP; ++e) acc[e] += __shfl_down(acc[e], off, 64);
    __shared__ double red[4][NEXP];
    int lane = tid & 63, w = tid >> 6;
    if (lane == 0)
#pragma unroll
        for (int e = 0; e < NEXP; ++e) red[w][e] = acc[e];
    __syncthreads();
    if (tid == 0) {
        double sc[NEXP], v[NEXP];
#pragma unroll
        for (int e = 0; e < NEXP; ++e) {
            double s = red[0][e] + red[1][e] + red[2][e] + red[3][e];
            sc[e] = 1.0 / (1.0 + exp(-s));
            v[e] = sc[e] + (double)bias[e];
        }
        int b0 = 0;
        for (int e = 1; e < NEXP; ++e) if (v[e] > v[b0]) b0 = e;
        int b1 = -1;
        for (int e = 0; e < NEXP; ++e)
            if (e != b0 && (b1 < 0 || v[e] > v[b1])) b1 = e;
        sel[t * 2] = b0; sel[t * 2 + 1] = b1;
        topsc[t * 2] = (float)sc[b0]; topsc[t * 2 + 1] = (float)sc[b1];
    }
}

// ------- stable counting sort into per-expert segments + inverse perm -------
__global__ __launch_bounds__(256) void sort_k(const int* __restrict__ sel,
                                              const float* __restrict__ topsc,
                                              int* __restrict__ tok_s,
                                              float* __restrict__ sc_s,
                                              int* __restrict__ counts,
                                              int* __restrict__ pos) {
    __shared__ int se[NTOK * TOPK];
    int tid = threadIdx.x;
    for (int i = tid; i < NTOK * TOPK; i += 256) se[i] = sel[i];
    __syncthreads();
    int wv = tid >> 6, lane = tid & 63;
    unsigned long long lower = (1ull << lane) - 1ull;
    for (int ei = 0; ei < 2; ++ei) {
        int e = wv * 2 + ei;
        int base = e * CAP_E;
        int off = 0;
        for (int c = 0; c < (NTOK * TOPK) / 64; ++c) {
            int slot = c * 64 + lane;
            bool m = (se[slot] == e);
            unsigned long long bal = __ballot(m);
            if (m) {
                int rank = off + __popcll(bal & lower);
                if (rank < CAP_E) {
                    tok_s[base + rank] = slot >> 1;  // TOPK = 2
                    sc_s[base + rank] = topsc[slot];
                    pos[slot] = base + rank;
                } else {
                    pos[slot] = -1;
                }
            }
            off += __popcll(bal);
        }
        int cnt = min(off, CAP_E);
        if (lane == 0) counts[e] = cnt;
        int padded = min((cnt + 127) & ~127, CAP_E);
        for (int r = cnt + lane; r < padded; r += 64) tok_s[base + r] = -1;
    }
}

// ---------- gather + scale -> rin bf16 (routed segs + shared block) ----------
__global__ __launch_bounds__(256) void build_rin(const float* __restrict__ x,
                                                 const int* __restrict__ tok_s,
                                                 const float* __restrict__ sc_s,
                                                 const int* __restrict__ counts,
                                                 bf16_t* __restrict__ rin) {
    int row = blockIdx.x;
    int tok; float sc = 1.0f;
    if (row >= SH_BASE) {
        tok = row - SH_BASE;
    } else {
        int e = row >> 10, r = row & (CAP_E - 1);
        int cnt = min(counts[e], CAP_E);
        int padded = min((cnt + 127) & ~127, CAP_E);
        if (r >= padded) return;
        if (r < cnt) { tok = tok_s[row]; sc = sc_s[row]; }
        else tok = -1;
    }
    int d0 = threadIdx.x * 8;
    bf16x8 o;
    if (tok >= 0) {
        const float* src = x + (long)tok * DIMM + d0;
        float4 a = *(const float4*)src;
        float4 b = *(const float4*)(src + 4);
        o[0] = (bf16_t)(a.x * sc); o[1] = (bf16_t)(a.y * sc);
        o[2] = (bf16_t)(a.z * sc); o[3] = (bf16_t)(a.w * sc);
        o[4] = (bf16_t)(b.x * sc); o[5] = (bf16_t)(b.y * sc);
        o[6] = (bf16_t)(b.z * sc); o[7] = (bf16_t)(b.w * sc);
    } else {
#pragma unroll
        for (int i = 0; i < 8; ++i) o[i] = (bf16_t)0.0f;
    }
    *(bf16x8*)(rin + (long)row * DIMM + d0) = o;
}

// ---------------- pipelined grouped GEMM, dbuf LDS ----------------
// PHASE 1: K=2048, B-tile row r -> (r>>4)&1 ? w3 : w1, weight row
//          n0h + (r>>5)*16 + (r&15); epilogue fuses SiLU, writes hB bf16.
// PHASE 2: K=1024, B = w2[g]; plain fp32 store to C2 (sorted-row space).

#define STAGE_A(kt, buf) do { \
    _Pragma("unroll") \
    for (int i_ = 0; i_ < 4; ++i_) \
        gl2lds16(arow[i_] + (kt) * 64, &lA[buf][(i_ * 256 + tid) * 8]); \
} while (0)

#define LOAD_B(kt, s) do { \
    _Pragma("unroll") \
    for (int i_ = 0; i_ < 4; ++i_) { \
        const float* bp_ = brow[i_] + (kt) * 64; \
        u##s[i_] = *(const float4*)bp_; \
        v##s[i_] = *(const float4*)(bp_ + 4); \
    } \
} while (0)

#define WRITE_B(s, buf) do { \
    _Pragma("unroll") \
    for (int i_ = 0; i_ < 4; ++i_) { \
        bf16x8 o_ = {(bf16_t)u##s[i_].x, (bf16_t)u##s[i_].y, \
                     (bf16_t)u##s[i_].z, (bf16_t)u##s[i_].w, \
                     (bf16_t)v##s[i_].x, (bf16_t)v##s[i_].y, \
                     (bf16_t)v##s[i_].z, (bf16_t)v##s[i_].w}; \
        *(bf16x8*)&lB[buf][slot[i_] * 8] = o_; \
    } \
} while (0)

#define MFMA_TILE(buf) do { \
    _Pragma("unroll") \
    for (int ki_ = 0; ki_ < 2; ++ki_) { \
        bf16x8 af_[4], bg_[4]; \
        int kc_ = ki_ * 4 + quad; \
        _Pragma("unroll") \
        for (int mi_ = 0; mi_ < 4; ++mi_) { \
            int row_ = wm + mi_ * 16 + l16; \
            af_[mi_] = *(const bf16x8*)&lA[buf][(row_ * 8 + (kc_ ^ (row_ & 7))) * 8]; \
        } \
        _Pragma("unroll") \
        for (int ni_ = 0; ni_ < 4; ++ni_) { \
            int row_ = wn + ni_ * 16 + l16; \
            bg_[ni_] = *(const bf16x8*)&lB[buf][(row_ * 8 + (kc_ ^ (row_ & 7))) * 8]; \
        } \
        _Pragma("unroll") \
        for (int mi_ = 0; mi_ < 4; ++mi_) \
            _Pragma("unroll") \
            for (int ni_ = 0; ni_ < 4; ++ni_) \
                acc[mi_][ni_] = __builtin_amdgcn_mfma_f32_16x16x32_bf16( \
                    af_[mi_], bg_[ni_], acc[mi_][ni_], 0, 0, 0); \
    } \
} while (0)

template <int PHASE>
__global__ __launch_bounds__(256, 2) void gemm_moe(
    const bf16_t* __restrict__ A0,
    const float* __restrict__ W1, const float* __restrict__ W3,
    const float* __restrict__ SW1, const float* __restrict__ SW3,
    bf16_t* __restrict__ hOut, float* __restrict__ C2,
    const int* __restrict__ counts) {
    constexpr int K = (PHASE == 1) ? 2048 : 1024;
    constexpr int KT = K / 64;
    int g = blockIdx.z;
    int base = (g < 8) ? g * CAP_E : SH_BASE;
    int M = NTOK;
    if (g < 8) {
        int c = min(counts[g], CAP_E);
        M = min((c + 127) & ~127, CAP_E);
    }
    int m0 = blockIdx.y * 128;
    if (m0 >= M) return;
    const bf16_t* A = A0 + (long)base * K;

    __shared__ bf16_t lA[2][128 * 64];
    __shared__ bf16_t lB[2][128 * 64];

    int tid = threadIdx.x;
    int lane = tid & 63, wv = tid >> 6;
    int quad = lane >> 4, l16 = lane & 15;
    int wm = (wv & 1) * 64, wn = (wv >> 1) * 64;
    int cc = tid & 7;
    int rbase = tid >> 3;

    // A staging source pointers (fixed across k-tiles)
    const bf16_t* arow[4];
#pragma unroll
    for (int i = 0; i < 4; ++i) {
        int row = i * 32 + rbase;
        arow[i] = A + (long)(m0 + row) * K + (cc ^ (row & 7)) * 8;
    }
    // B staging: row pointers + swizzled LDS slots
    const float* brow[4];
    int slot[4];
#pragma unroll
    for (int i = 0; i < 4; ++i) {
        int r = i * 32 + rbase;
        const float* p;
        if (PHASE == 1) {
            int colw = (blockIdx.x << 6) + ((r >> 5) << 4) + (r & 15);
            int type = (r >> 4) & 1;
            if (g < 8) p = (type ? W3 : W1) + ((long)g << 21) + (long)colw * DIMM;
            else       p = (type ? SW3 : SW1) + (long)colw * DIMM;
        } else {
            int n = (blockIdx.x << 7) + r;
            p = ((g < 8) ? W1 + ((long)g << 21) : SW1) + (long)n * HIDD;
        }
        brow[i] = p + cc * 8;
        slot[i] = r * 8 + (cc ^ (r & 7));
    }

    f32x4 acc[4][4];
#pragma unroll
    for (int i = 0; i < 4; ++i)
#pragma unroll
        for (int j = 0; j < 4; ++j) acc[i][j] = (f32x4){0.f, 0.f, 0.f, 0.f};

    float4 u0[4], v0[4], u1[4], v1[4];
    // prologue: stage tile 0, prefetch B regs for tile 1
    STAGE_A(0, 0);
    LOAD_B(0, 0);
    WRITE_B(0, 0);
    LOAD_B(1, 1);
    __syncthreads();

    for (int kt = 0; kt < KT; kt += 2) {
        // even sub-iter: consume buf0 (tile kt)
        STAGE_A(kt + 1, 1);
        if (kt + 2 < KT) LOAD_B(kt + 2, 0);
        MFMA_TILE(0);
        WRITE_B(1, 1);
        __syncthreads();
        // odd sub-iter: consume buf1 (tile kt+1)
        if (kt + 2 < KT) {
            STAGE_A(kt + 2, 0);
            if (kt + 3 < KT) LOAD_B(kt + 3, 1);
        }
        MFMA_TILE(1);
        if (kt + 2 < KT) WRITE_B(0, 0);
        __syncthreads();
    }

    if (PHASE == 1) {
        // acc[mi][ni]: ni even = gate, ni odd = up, colgroup = (wn>>5)+(ni>>1)
#pragma unroll
        for (int mi = 0; mi < 4; ++mi)
#pragma unroll
            for (int r = 0; r < 4; ++r) {
                long row = base + m0 + wm + mi * 16 + quad * 4 + r;
#pragma unroll
                for (int j = 0; j < 2; ++j) {
                    float gt = acc[mi][2 * j][r];
                    float up = acc[mi][2 * j + 1][r];
                    float s = gt / (1.f + __expf(-gt));
                    int col = (blockIdx.x << 6) + ((wn >> 5) + j) * 16 + l16;
                    hOut[row * HIDD + col] = (bf16_t)(s * up);
                }
            }
    } else {
#pragma unroll
        for (int mi = 0; mi < 4; ++mi)
#pragma unroll
            for (int r = 0; r < 4; ++r) {
                long row = base + m0 + wm + mi * 16 + quad * 4 + r;
#pragma unroll
                for (int ni = 0; ni < 4; ++ni) {
                    int col = (blockIdx.x << 7) + wn + ni * 16 + l16;
                    C2[row * DIMM + col] = acc[mi][ni][r];
                }
            }
    }
}

// ---------------- combine: out[t] = shared + slot0 + slot1 ----------------
__global__ __launch_bounds__(256) void combine_k(const float* __restrict__ C2,
                                                 const int* __restrict__ pos,
                                                 float* __restrict__ out) {
    int t = blockIdx.x;
    int c = threadIdx.x * 8;
    int p0 = pos[t * 2], p1 = pos[t * 2 + 1];
    const float* sh = C2 + (long)(SH_BASE + t) * DIMM + c;
    float4 a = *(const float4*)sh;
    float4 b = *(const float4*)(sh + 4);
    if (p0 >= 0) {
        const float* q = C2 + (long)p0 * DIMM + c;
        float4 qa = *(const float4*)q, qb = *(const float4*)(q + 4);
        a.x += qa.x; a.y += qa.y; a.z += qa.z; a.w += qa.w;
        b.x += qb.x; b.y += qb.y; b.z += qb.z; b.w += qb.w;
    }
    if (p1 >= 0) {
        const float* q = C2 + (long)p1 * DIMM + c;
        float4 qa = *(const float4*)q, qb = *(const float4*)(q + 4);
        a.x += qa.x; a.y += qa.y; a.z += qa.z; a.w += qa.w;
        b.x += qb.x; b.y += qb.y; b.z += qb.z; b.w += qb.w;
    }
    float* op = out + (long)t * DIMM + c;
    *(float4*)op = a;
    *(float4*)(op + 4) = b;
}

extern "C" void kernel_launch(void* const* d_in, const int* in_sizes, int n_in,
                              void* d_out, int out_size, void* d_ws, size_t ws_size,
                              hipStream_t stream) {
    const float* x    = (const float*)d_in[0];
    const float* bias = (const float*)d_in[1];
    const float* gw   = (const float*)d_in[2];
    const float* w1   = (const float*)d_in[3];
    const float* w2   = (const float*)d_in[4];
    const float* w3   = (const float*)d_in[5];
    const float* sw1  = (const float*)d_in[6];
    const float* sw2  = (const float*)d_in[7];
    const float* sw3  = (const float*)d_in[8];
    float* out = (float*)d_out;

    char* p = (char*)d_ws;
    auto alloc = [&](size_t bytes) {
        char* r = p;
        p += (bytes + 255) & ~(size_t)255;
        return r;
    };
    bf16_t* rin   = (bf16_t*)alloc((size_t)NROW * DIMM * 2);   // 40 MB
    bf16_t* hB    = (bf16_t*)alloc((size_t)NROW * HIDD * 2);   // 20 MB
    float*  C2    = (float*)alloc((size_t)NROW * DIMM * 4);    // 80 MB
    int*   sel    = (int*)alloc(NTOK * TOPK * 4);
    float* topsc  = (float*)alloc(NTOK * TOPK * 4);
    int*   tok_s  = (int*)alloc(SH_BASE * 4);
    float* sc_s   = (float*)alloc(SH_BASE * 4);
    int*   pos    = (int*)alloc(NTOK * TOPK * 4);
    int*   counts = (int*)alloc(256);

    router_k<<<NTOK, 256, 0, stream>>>(x, gw, bias, sel, topsc);
    sort_k<<<1, 256, 0, stream>>>(sel, topsc, tok_s, sc_s, counts, pos);
    build_rin<<<NROW, 256, 0, stream>>>(x, tok_s, sc_s, counts, rin);

    // GEMM1 + fused SiLU: hB[g] = silu(A@w1^T) * (A@w3^T)   (9 groups)
    gemm_moe<1><<<dim3(16, 16, 9), 256, 0, stream>>>(
        rin, w1, w3, sw1, sw3, hB, nullptr, counts);

    // GEMM2: C2[g] = hB[g] @ w2[g]^T   (9 groups, plain fp32 store)
    gemm_moe<2><<<dim3(16, 16, 9), 256, 0, stream>>>(
        hB, w2, nullptr, sw2, nullptr, nullptr, C2, counts);

    combine_k<<<NTOK, 256, 0, stream>>>(C2, pos, out);
}